// Round 1
// 541.563 us; speedup vs baseline: 1.1274x; 1.1274x over previous
//
#include <hip/hip_runtime.h>
#include <math.h>

// Problem constants
#define BATCH 2
#define SEQ   2048
#define DIM   2048
#define NH    16
#define HD    128
#define EPS   1e-6f

typedef _Float16 f16x8 __attribute__((ext_vector_type(8)));
typedef _Float16 f16x4 __attribute__((ext_vector_type(4)));
typedef _Float16 f16x2 __attribute__((ext_vector_type(2)));
typedef float    f32x4 __attribute__((ext_vector_type(4)));

#define MFMA_F16 __builtin_amdgcn_mfma_f32_16x16x32_f16

// W pre-scale: W*1024 keeps W_lo (~2^-12 * 0.02) in fp16 normal range.
#define WSCALE    1024.0f
#define INV_WSCALE 0.0009765625f

// ---------------------------------------------------------------------------
// fp32 -> fp16 (single), 4 el/thread
// ---------------------------------------------------------------------------
__global__ __launch_bounds__(256) void cvt_f16(
    const float* __restrict__ in, _Float16* __restrict__ out) {
  int i = blockIdx.x * 256 + threadIdx.x;
  float4 v = ((const float4*)in)[i];
  f16x4 o;
  o[0] = (_Float16)v.x; o[1] = (_Float16)v.y;
  o[2] = (_Float16)v.z; o[3] = (_Float16)v.w;
  ((f16x4*)out)[i] = o;
}

// ---------------------------------------------------------------------------
// fp32 -> (hi, lo) fp16 of value*1024 (weights)
// ---------------------------------------------------------------------------
__global__ __launch_bounds__(256) void split_f16s(
    const float* __restrict__ in, _Float16* __restrict__ hi,
    _Float16* __restrict__ lo) {
  int i = blockIdx.x * 256 + threadIdx.x;
  float4 v = ((const float4*)in)[i];
  f16x4 h, l;
  float s;
  s = v.x * WSCALE; h[0] = (_Float16)s; l[0] = (_Float16)(s - (float)h[0]);
  s = v.y * WSCALE; h[1] = (_Float16)s; l[1] = (_Float16)(s - (float)h[1]);
  s = v.z * WSCALE; h[2] = (_Float16)s; l[2] = (_Float16)(s - (float)h[2]);
  s = v.w * WSCALE; h[3] = (_Float16)s; l[3] = (_Float16)(s - (float)h[3]);
  ((f16x4*)hi)[i] = h;
  ((f16x4*)lo)[i] = l;
}

// ---------------------------------------------------------------------------
// 8-phase 2-pass fp16 MFMA GEMM:  C[M,N] = A[M,K] @ (Bh+Bl)[N,K]^T * outscale
// BM=256 BN=128 BK=64, 8 waves (2x4), per-wave out 128x32.
// LDS: 2 buffers x (A 256x64 + Bh 128x64 + Bl 128x64) f16 = 128 KiB.
// Per iter = 2 K-tiles = 8 phases x {ds_read ; 2 global_load_lds ; barrier ;
// 16 MFMA under setprio}.  Counted vmcnt(2) at ph0/1/4/5 only (loads stay in
// flight across 4 barriers).  XOR-swizzle (chunk ^= row&7 within 128B row)
// applied on the per-lane GLOBAL source + on ds_read addrs (LDS dest linear).
// ---------------------------------------------------------------------------
#define BM8 256
#define BN8 128

__global__ __launch_bounds__(512, 2) void gemm_2p8(
    const _Float16* __restrict__ Ag, const _Float16* __restrict__ Bhg,
    const _Float16* __restrict__ Blg, float* __restrict__ C,
    int M, int N, int K, float outscale) {
  // stack rows: [0,256) = A, [256,384) = Bh, [384,512) = Bl; 64 f16 per row.
  __shared__ __align__(16) _Float16 smem[2][512][64];

  const int t = threadIdx.x;
  const int w = t >> 6, lane = t & 63;
  const int bm = blockIdx.y * BM8, bn = blockIdx.x * BN8;
  const int wr = (w >> 2) * 128;      // wave row offset (2 wave-rows)
  const int wc = (w & 3) * 32;        // wave col offset (4 wave-cols)
  const int quad = lane >> 4, c15 = lane & 15;

  const _Float16* baseA  = Ag  + (size_t)bm * K;
  const _Float16* baseBh = Bhg + (size_t)bn * K;
  const _Float16* baseBl = Blg + (size_t)bn * K;

  // staging: chunk = 1 KiB = 8 rows x 128B.  lane covers row (l>>3), 16B slot
  // (l&7); source slot pre-swizzled so LDS[row][slot] holds global slot^(row&7).
  const int lrow = lane >> 3;
  const int lswz = ((lane & 7) ^ lrow) * 8;    // f16 units

  // fragment read column offsets (f16 units).  (row&7) == (c15&7) for all
  // frag rows (wr, wc, m*16, 256, 384 all ≡ 0 mod 8).
  const int col0 = (((0 * 4) + quad) ^ (c15 & 7)) * 8;   // ks=0
  const int col1 = (((1 * 4) + quad) ^ (c15 & 7)) * 8;   // ks=1

  f32x4 acc[8][2] = {};
  f16x8 a0[8], a1[8], bh[2][2], bl[2][2];

  // wave-uniform staging of chunks q*16+2w, q*16+2w+1 into buffer `buf`
#define STAGE2(buf, q, kofs)                                                   \
  {                                                                            \
    _Pragma("unroll")                                                          \
    for (int e = 0; e < 2; ++e) {                                              \
      int c = (q) * 16 + 2 * w + e;                                            \
      int rl = c * 8 + lrow;                                                   \
      const _Float16* g;                                                       \
      if ((q) < 2)        g = baseA  + (size_t)rl * K;                         \
      else if ((q) == 2)  g = baseBh + (size_t)(rl - 256) * K;                 \
      else                g = baseBl + (size_t)(rl - 384) * K;                 \
      __builtin_amdgcn_global_load_lds(                                        \
          (const __attribute__((address_space(1))) unsigned int*)(g + (kofs) + lswz), \
          (__attribute__((address_space(3))) unsigned int*)(&smem[buf][(c) * 8][0]),  \
          16, 0, 0);                                                           \
    }                                                                          \
  }

#define LDA8(dst, colv, buf)                                                   \
  _Pragma("unroll")                                                            \
  for (int m2 = 0; m2 < 8; ++m2)                                               \
    dst[m2] = *(const f16x8*)(&smem[buf][wr + m2 * 16 + c15][colv]);

#define LDB2(dst, rbase, colv, buf)                                            \
  _Pragma("unroll")                                                            \
  for (int n2 = 0; n2 < 2; ++n2)                                               \
    dst[n2] = *(const f16x8*)(&smem[buf][(rbase) + wc + n2 * 16 + c15][colv]);

#define MF16(af, bf)                                                           \
  _Pragma("unroll")                                                            \
  for (int m2 = 0; m2 < 8; ++m2)                                               \
    _Pragma("unroll")                                                          \
    for (int n2 = 0; n2 < 2; ++n2)                                             \
      acc[m2][n2] = MFMA_F16(af[m2], bf[n2], acc[m2][n2], 0, 0, 0);

#define PH_TOP()                                                               \
  __builtin_amdgcn_s_barrier();                                                \
  __builtin_amdgcn_sched_barrier(0);

  // prologue: tile 0 -> buf0 (issue order: A-low, A-high, Bh, Bl)
  STAGE2(0, 0, 0) STAGE2(0, 1, 0) STAGE2(0, 2, 0) STAGE2(0, 3, 0)

  const int NI = K >> 7;   // 2 K-tiles per iter
  for (int i = 0; i < NI; ++i) {
    const int kB = (i << 7) + 64;     // buf1 tile (staged ph0-3)
    const int kN = (i << 7) + 128;    // next buf0 tile (staged ph4-7)
    const bool more = (i + 1 < NI);

    // ---- ph0: buf0 pass-h ks0 ----   (needs buf0 A+Bh -> vmcnt(2))
    asm volatile("s_waitcnt vmcnt(2)" ::: "memory");
    PH_TOP();
    LDA8(a0, col0, 0);
    LDB2(bh[0], 256, col0, 0);
    STAGE2(1, 0, kB);
    __builtin_amdgcn_s_setprio(1);
    MF16(a0, bh[0]);
    __builtin_amdgcn_s_setprio(0);

    // ---- ph1: buf0 pass-h ks1 ----   (vmcnt(2) forces buf0 Bl for ph2/3)
    asm volatile("s_waitcnt vmcnt(2)" ::: "memory");
    PH_TOP();
    LDA8(a1, col1, 0);
    LDB2(bh[1], 256, col1, 0);
    STAGE2(1, 1, kB);
    __builtin_amdgcn_s_setprio(1);
    MF16(a1, bh[1]);
    __builtin_amdgcn_s_setprio(0);

    // ---- ph2: buf0 pass-l ks0 ----
    PH_TOP();
    LDB2(bl[0], 384, col0, 0);
    STAGE2(1, 2, kB);
    __builtin_amdgcn_s_setprio(1);
    MF16(a0, bl[0]);
    __builtin_amdgcn_s_setprio(0);

    // ---- ph3: buf0 pass-l ks1 ----
    PH_TOP();
    LDB2(bl[1], 384, col1, 0);
    STAGE2(1, 3, kB);
    __builtin_amdgcn_s_setprio(1);
    MF16(a1, bl[1]);
    __builtin_amdgcn_s_setprio(0);

    // ---- ph4: buf1 pass-h ks0 ----   (needs buf1 A+Bh -> vmcnt(2))
    asm volatile("s_waitcnt vmcnt(2)" ::: "memory");
    PH_TOP();
    LDA8(a0, col0, 1);
    LDB2(bh[0], 256, col0, 1);
    if (more) STAGE2(0, 0, kN);
    __builtin_amdgcn_s_setprio(1);
    MF16(a0, bh[0]);
    __builtin_amdgcn_s_setprio(0);

    // ---- ph5: buf1 pass-h ks1 ----   (forces buf1 Bl; drain on last iter)
    if (more) { asm volatile("s_waitcnt vmcnt(2)" ::: "memory"); }
    else      { asm volatile("s_waitcnt vmcnt(0)" ::: "memory"); }
    PH_TOP();
    LDA8(a1, col1, 1);
    LDB2(bh[1], 256, col1, 1);
    if (more) STAGE2(0, 1, kN);
    __builtin_amdgcn_s_setprio(1);
    MF16(a1, bh[1]);
    __builtin_amdgcn_s_setprio(0);

    // ---- ph6: buf1 pass-l ks0 ----
    PH_TOP();
    LDB2(bl[0], 384, col0, 1);
    if (more) STAGE2(0, 2, kN);
    __builtin_amdgcn_s_setprio(1);
    MF16(a0, bl[0]);
    __builtin_amdgcn_s_setprio(0);

    // ---- ph7: buf1 pass-l ks1 ----
    PH_TOP();
    LDB2(bl[1], 384, col1, 1);
    if (more) STAGE2(0, 3, kN);
    __builtin_amdgcn_s_setprio(1);
    MF16(a1, bl[1]);
    __builtin_amdgcn_s_setprio(0);
  }

  // C/D layout: col = lane&15, row = (lane>>4)*4 + reg
  #pragma unroll
  for (int m2 = 0; m2 < 8; ++m2)
    #pragma unroll
    for (int n2 = 0; n2 < 2; ++n2) {
      int col = bn + wc + 16 * n2 + c15;
      #pragma unroll
      for (int r = 0; r < 4; ++r) {
        int row = bm + wr + 16 * m2 + quad * 4 + r;
        C[(size_t)row * N + col] = acc[m2][n2][r] * outscale;
      }
    }
#undef STAGE2
#undef LDA8
#undef LDB2
#undef MF16
#undef PH_TOP
}

// ---------------------------------------------------------------------------
// RMSNorm + RoPE on q,k of qkv[b,s,6144]; emits Q fp16 (single) and K hi/lo
// fp16, layout [b,h,s,d].
// ---------------------------------------------------------------------------
__global__ __launch_bounds__(256) void rmsrope_f16(
    const float* __restrict__ qkv, const float* __restrict__ cosb,
    const float* __restrict__ sinb, _Float16* __restrict__ Qg,
    _Float16* __restrict__ Khg, _Float16* __restrict__ Klg) {
  const int blk = blockIdx.x;           // b*SEQ + s
  const int b = blk >> 11, s = blk & (SEQ - 1);
  const int wave = threadIdx.x >> 6, lane = threadIdx.x & 63;
  const float* base = qkv + (size_t)blk * (3 * DIM);
  const float c  = cosb[s * HD + 2 * lane];
  const float sn = sinb[s * HD + 2 * lane];
  #pragma unroll
  for (int h = wave; h < NH; h += 4) {
    float2 q = *(const float2*)(base + h * HD + 2 * lane);
    float2 k = *(const float2*)(base + DIM + h * HD + 2 * lane);
    float ssq = q.x * q.x + q.y * q.y;
    float ssk = k.x * k.x + k.y * k.y;
    #pragma unroll
    for (int off = 32; off >= 1; off >>= 1) {
      ssq += __shfl_xor(ssq, off, 64);
      ssk += __shfl_xor(ssk, off, 64);
    }
    float rq = rsqrtf(ssq * (1.0f / HD) + EPS);
    float rk = rsqrtf(ssk * (1.0f / HD) + EPS);
    float q1 = q.x * rq, q2 = q.y * rq;
    float k1 = k.x * rk, k2 = k.y * rk;
    float qy1 = q1 * c - q2 * sn, qy2 = q1 * sn + q2 * c;
    float ky1 = k1 * c - k2 * sn, ky2 = k1 * sn + k2 * c;
    size_t o = ((size_t)(b * NH + h) * SEQ + s) * HD + 2 * lane;
    f16x2 qo, kh, kl;
    qo[0] = (_Float16)qy1; qo[1] = (_Float16)qy2;
    kh[0] = (_Float16)ky1; kl[0] = (_Float16)(ky1 - (float)kh[0]);
    kh[1] = (_Float16)ky2; kl[1] = (_Float16)(ky2 - (float)kh[1]);
    *(f16x2*)(Qg  + o) = qo;
    *(f16x2*)(Khg + o) = kh;
    *(f16x2*)(Klg + o) = kl;
  }
}

// ---------------------------------------------------------------------------
// V transpose: qkv v-slice [64 s][128 d] fp32 -> Vt [b,h,d,s] single fp16.
// ---------------------------------------------------------------------------
__global__ __launch_bounds__(256) void vtrans_f16(
    const float* __restrict__ qkv, _Float16* __restrict__ Vt) {
  __shared__ _Float16 L[64 * 132];
  const int t = threadIdx.x;
  const int s0 = blockIdx.x * 64, h = blockIdx.y, b = blockIdx.z;
  const float* src = qkv + ((size_t)(b * SEQ + s0)) * (3 * DIM) + 2 * DIM + h * HD;
  #pragma unroll
  for (int it = 0; it < 8; ++it) {
    int f = t + it * 256;
    int r = f >> 5, c4 = f & 31;
    float4 v = *(const float4*)(src + (size_t)r * (3 * DIM) + c4 * 4);
    f16x4 o;
    o[0] = (_Float16)v.x; o[1] = (_Float16)v.y;
    o[2] = (_Float16)v.z; o[3] = (_Float16)v.w;
    *(f16x4*)(&L[r * 132 + c4 * 4]) = o;
  }
  __syncthreads();
  const int d = t >> 1, sc = (t & 1) * 32;
  size_t dst = ((size_t)((b * NH + h) * HD + d)) * SEQ + s0 + sc;
  #pragma unroll
  for (int j = 0; j < 8; ++j) {
    f16x4 o;
    o[0] = L[(sc + 4 * j + 0) * 132 + d];
    o[1] = L[(sc + 4 * j + 1) * 132 + d];
    o[2] = L[(sc + 4 * j + 2) * 132 + d];
    o[3] = L[(sc + 4 * j + 3) * 132 + d];
    *(f16x4*)(Vt + dst + j * 4) = o;
  }
}

// ---------------------------------------------------------------------------
// fp16 MFMA flash attention, fixed-max softmax.
// QK^T: Q single fp16 x (Kh + Kl) = 2 passes.  PV: P fp16 x V fp16 = 1 pass.
// 48 MFMA / K-chunk.  LDS: Kh/Kl/Vt 8 KB each + P 10 KB = 34 KB.
// ---------------------------------------------------------------------------
#define QT 128
#define KC 32

__global__ __launch_bounds__(256, 2) void flash_f16(
    const _Float16* __restrict__ Qg, const _Float16* __restrict__ Khg,
    const _Float16* __restrict__ Klg, const _Float16* __restrict__ Vtg,
    _Float16* __restrict__ Og) {
  // shorts(f16): Kh [0,4096)  Kl [4096,8192)  Vt [8192,12288)
  // P [12288,17408): per wave [32][40].  Q staging reuses [0,16384).
  __shared__ __align__(16) _Float16 sm[17408];

  const int t = threadIdx.x, w = t >> 6, lane = t & 63;
  const int quad = lane >> 4, c15 = lane & 15;
  const int hy = blockIdx.y, bz = blockIdx.z;
  const int bh = bz * NH + hy;
  const int q0 = blockIdx.x * QT;
  const int wr = w * 32;

  // ---- stage Q [128][128] f16 once; fragments -> registers ----
  {
    const _Float16* qsrc = Qg + ((size_t)bh * SEQ + q0) * HD;
    #pragma unroll
    for (int p = 0; p < 8; ++p) {
      int ci = p * 256 + t;
      int r = ci >> 4, c8 = (ci & 15) ^ (r & 15);
      __builtin_amdgcn_global_load_lds(
          (const __attribute__((address_space(1))) unsigned int*)(qsrc + (size_t)r * HD + c8 * 8),
          (__attribute__((address_space(3))) unsigned int*)(sm + ci * 8), 16, 0, 0);
    }
  }
  __syncthreads();
  f16x8 qf[2][4];  // [mf][ks]
  #pragma unroll
  for (int mf = 0; mf < 2; ++mf)
    #pragma unroll
    for (int ks = 0; ks < 4; ++ks) {
      int m = wr + mf * 16 + c15;
      int c8 = ks * 4 + quad;
      qf[mf][ks] = *(const f16x8*)(sm + (m * 16 + (c8 ^ (m & 15))) * 8);
    }

  float lrow[8];
  f32x4 oacc[2][8];
  #pragma unroll
  for (int i = 0; i < 8; ++i) lrow[i] = 0.f;
  #pragma unroll
  for (int mf = 0; mf < 2; ++mf)
    #pragma unroll
    for (int nf = 0; nf < 8; ++nf) oacc[mf][nf] = (f32x4){0.f, 0.f, 0.f, 0.f};

  const float sl = 0.12751744f;       // (1/sqrt(128)) * log2(e)
  const float M2 = 16.322231f;        // sqrt(128) * log2(e)  (|score|<=sqrt(128))
  _Float16* Pw = sm + 12288 + w * 1280;

  for (int kk = 0; kk < SEQ; kk += KC) {
    __syncthreads();  // all waves done with previous tiles (and Q frags at kk=0)
    if (w == 0 || w == 1) {   // Kh / Kl tiles [32][128]
      const _Float16* src = (w == 0 ? Khg : Klg) + ((size_t)bh * SEQ + kk) * HD;
      #pragma unroll
      for (int p = 0; p < 8; ++p) {
        int ci = p * 64 + lane;
        int r = ci >> 4, c8 = (ci & 15) ^ (r & 15);
        __builtin_amdgcn_global_load_lds(
            (const __attribute__((address_space(1))) unsigned int*)(src + (size_t)r * HD + c8 * 8),
            (__attribute__((address_space(3))) unsigned int*)(sm + w * 4096 + ci * 8), 16, 0, 0);
      }
    } else if (w == 2) {      // V^T tile [128 d][32 s]
      const _Float16* src = Vtg + (size_t)bh * HD * SEQ + kk;
      #pragma unroll
      for (int p = 0; p < 8; ++p) {
        int ci = p * 64 + lane;
        int d = ci >> 2, c8 = (ci & 3) ^ (d & 3);
        __builtin_amdgcn_global_load_lds(
            (const __attribute__((address_space(1))) unsigned int*)(src + (size_t)d * SEQ + c8 * 8),
            (__attribute__((address_space(3))) unsigned int*)(sm + 8192 + ci * 8), 16, 0, 0);
      }
    }
    __syncthreads();

    // ---- S = Q K^T (2 passes: Kh then Kl) ----
    f32x4 accs[2][2] = {};
    #pragma unroll
    for (int nf = 0; nf < 2; ++nf) {
      f16x8 kh[4], kl[4];
      #pragma unroll
      for (int ks = 0; ks < 4; ++ks) {
        int n = nf * 16 + c15;
        int c8 = ks * 4 + quad;
        int slot = (n * 16 + (c8 ^ (n & 15))) * 8;
        kh[ks] = *(const f16x8*)(sm + slot);
        kl[ks] = *(const f16x8*)(sm + 4096 + slot);
      }
      #pragma unroll
      for (int ks = 0; ks < 4; ++ks) {
        accs[0][nf] = MFMA_F16(qf[0][ks], kh[ks], accs[0][nf], 0, 0, 0);
        accs[1][nf] = MFMA_F16(qf[1][ks], kh[ks], accs[1][nf], 0, 0, 0);
      }
      #pragma unroll
      for (int ks = 0; ks < 4; ++ks) {
        accs[0][nf] = MFMA_F16(qf[0][ks], kl[ks], accs[0][nf], 0, 0, 0);
        accs[1][nf] = MFMA_F16(qf[1][ks], kl[ks], accs[1][nf], 0, 0, 0);
      }
    }

    // ---- fixed-shift softmax weights (lane-local denominator) ----
    #pragma unroll
    for (int mf = 0; mf < 2; ++mf)
      #pragma unroll
      for (int reg = 0; reg < 4; ++reg) {
        float p0 = exp2f(fmaf(accs[mf][0][reg], sl, -M2));
        float p1 = exp2f(fmaf(accs[mf][1][reg], sl, -M2));
        lrow[mf * 4 + reg] += p0 + p1;
        int prow = mf * 16 + quad * 4 + reg;
        Pw[prow * 40 + c15]      = (_Float16)p0;
        Pw[prow * 40 + c15 + 16] = (_Float16)p1;
      }

    // ---- O += P V (single pass) ----
    f16x8 pa0 = *(const f16x8*)(Pw + (c15) * 40 + quad * 8);
    f16x8 pa1 = *(const f16x8*)(Pw + (16 + c15) * 40 + quad * 8);
    #pragma unroll
    for (int nf = 0; nf < 8; ++nf) {
      int dd = nf * 16 + c15;
      int slot = (dd * 4 + (quad ^ (dd & 3))) * 8;
      f16x8 vv = *(const f16x8*)(sm + 8192 + slot);
      oacc[0][nf] = MFMA_F16(pa0, vv, oacc[0][nf], 0, 0, 0);
      oacc[1][nf] = MFMA_F16(pa1, vv, oacc[1][nf], 0, 0, 0);
    }
  }

  // ---- epilogue: denominator reduce + O write (single fp16) ----
  #pragma unroll
  for (int i = 0; i < 8; ++i) {
    float s = lrow[i];
    #pragma unroll
    for (int off = 8; off >= 1; off >>= 1) s += __shfl_xor(s, off, 64);
    lrow[i] = s;
  }
  #pragma unroll
  for (int mf = 0; mf < 2; ++mf)
    #pragma unroll
    for (int reg = 0; reg < 4; ++reg) {
      float inv = 1.0f / lrow[mf * 4 + reg];
      int row = q0 + wr + mf * 16 + quad * 4 + reg;
      size_t ob = ((size_t)bz * SEQ + row) * DIM + hy * HD + c15;
      #pragma unroll
      for (int nf = 0; nf < 8; ++nf)
        Og[ob + nf * 16] = (_Float16)(oacc[mf][nf][reg] * inv);
    }
}

// ---------------------------------------------------------------------------
// Launch.  Workspace (<= 201 MB):
//   [0, 100663296)          qkv fp32 -> later O16 + Wph/Wpl
//   R = +100663296:
//     pre-gemm1 : x16 [R,+16.7M)  Wh [R+16.7M,+25.2M)  Wl [R+41.9M,+25.2M)
//     post-gemm1: Q16 [R) Kh [R+16.7M) Kl [R+33.6M) Vt [R+50.3M) (16.7M each)
//   O16 at ws[0,16.7M), Wph ws+16.7M, Wpl ws+25.2M (after qkv consumed).
// ---------------------------------------------------------------------------
extern "C" void kernel_launch(void* const* d_in, const int* in_sizes, int n_in,
                              void* d_out, int out_size, void* d_ws, size_t ws_size,
                              hipStream_t stream) {
  const float* x     = (const float*)d_in[0];
  const float* cosb  = (const float*)d_in[1];
  const float* sinb  = (const float*)d_in[2];
  const float* Wqkv  = (const float*)d_in[3];
  const float* Wproj = (const float*)d_in[4];
  float* out = (float*)d_out;

  char* ws = (char*)d_ws;
  float* qkv = (float*)ws;
  char* R = ws + 100663296;
  _Float16* x16 = (_Float16*)(R);
  _Float16* Wh  = (_Float16*)(R + 16777216);
  _Float16* Wl  = (_Float16*)(R + 41943040);
  _Float16* Q16 = (_Float16*)(R);
  _Float16* Kh  = (_Float16*)(R + 16777216);
  _Float16* Kl  = (_Float16*)(R + 33554432);
  _Float16* Vt  = (_Float16*)(R + 50331648);
  _Float16* O16 = (_Float16*)(ws);
  _Float16* Wph = (_Float16*)(ws + 16777216);
  _Float16* Wpl = (_Float16*)(ws + 25165824);

  cvt_f16  <<<8192,  256, 0, stream>>>(x, x16);
  split_f16s<<<12288, 256, 0, stream>>>(Wqkv, Wh, Wl);
  gemm_2p8<<<dim3(48, 16), 512, 0, stream>>>(x16, Wh, Wl, qkv, 4096, 6144, 2048, INV_WSCALE);
  rmsrope_f16<<<4096, 256, 0, stream>>>(qkv, cosb, sinb, Q16, Kh, Kl);
  vtrans_f16<<<dim3(32, NH, BATCH), 256, 0, stream>>>(qkv, Vt);
  split_f16s<<<4096, 256, 0, stream>>>(Wproj, Wph, Wpl);   // after qkv consumed
  flash_f16<<<dim3(SEQ / QT, NH, BATCH), 256, 0, stream>>>(Q16, Kh, Kl, Vt, O16);
  gemm_2p8<<<dim3(16, 16), 512, 0, stream>>>(O16, Wph, Wpl, out, 4096, 2048, 2048, INV_WSCALE);
}